// Round 1
// baseline (225.404 us; speedup 1.0000x reference)
//
#include <hip/hip_runtime.h>

#define B_N 256
#define C_N 50000
#define D_N 512
#define ALPHA 0.5f

// Kernel 1: recover labels from one-hot rows + per-class counts.
// onehot is [B, C] fp32 with exactly one 1.0 per row. C_N % 4 == 0 so every
// row is float4-aligned. 12.8M floats -> 3.2M float4 lanes, fully coalesced.
__global__ __launch_bounds__(256) void find_labels(
        const float* __restrict__ onehot,
        int* __restrict__ labels,
        int* __restrict__ counts) {
    int idx = blockIdx.x * 256 + threadIdx.x;           // float4 index
    const int total4 = B_N * C_N / 4;
    if (idx >= total4) return;
    const float4* p = (const float4*)onehot;
    float4 v = p[idx];
    if (v.x != 0.f || v.y != 0.f || v.z != 0.f || v.w != 0.f) {
        int base = idx * 4;
        float f[4] = {v.x, v.y, v.z, v.w};
#pragma unroll
        for (int k = 0; k < 4; ++k) {
            if (f[k] != 0.f) {
                int g = base + k;
                int b = g / C_N;
                int c = g - b * C_N;
                labels[b] = c;                          // exactly one writer per b
                atomicAdd(&counts[c], 1);
            }
        }
    }
}

// Kernel 2: result[b] = sum_d (x[b][d] - centers[label_b][d])^2
// 256 blocks x 128 threads; each thread owns one float4 of the 512-dim row.
__global__ __launch_bounds__(128) void sq_dist(
        const float* __restrict__ x,
        const float* __restrict__ centers,
        const int* __restrict__ labels,
        float* __restrict__ result) {
    int b = blockIdx.x;
    int t = threadIdx.x;                                // 0..127
    int lab = labels[b];
    float4 xv = ((const float4*)(x + (size_t)b * D_N))[t];
    float4 cv = ((const float4*)(centers + (size_t)lab * D_N))[t];
    float dx = xv.x - cv.x, dy = xv.y - cv.y, dz = xv.z - cv.z, dw = xv.w - cv.w;
    float s = dx * dx + dy * dy + dz * dz + dw * dw;
    // wave64 butterfly, then combine 2 waves via LDS
#pragma unroll
    for (int off = 32; off > 0; off >>= 1) s += __shfl_down(s, off, 64);
    __shared__ float ws[2];
    if ((t & 63) == 0) ws[t >> 6] = s;
    __syncthreads();
    if (t == 0) result[b] = ws[0] + ws[1];
}

// Kernel 3: new_centers row update. One block per class row (50000 blocks,
// 128 threads, one float4/thread = 512 floats). Untouched rows (n==0, the
// overwhelming majority) are a pure coalesced copy. Touched rows (<=256)
// scan the tiny label list (L1-resident) to accumulate sum_x.
//   new[c] = centers[c]*(1 - a*n/(n+1)) + (a/(n+1)) * sum_{label_b=c} x[b]
__global__ __launch_bounds__(128) void update_centers(
        const float* __restrict__ x,
        const float* __restrict__ centers,
        const int* __restrict__ labels,
        const int* __restrict__ counts,
        float* __restrict__ newc) {
    int c = blockIdx.x;
    int t = threadIdx.x;
    int n = counts[c];                                  // scalar, wave-uniform
    float4 cv = ((const float4*)(centers + (size_t)c * D_N))[t];
    float4 res;
    if (n == 0) {
        res = cv;
    } else {
        float4 sx = make_float4(0.f, 0.f, 0.f, 0.f);
        for (int b = 0; b < B_N; ++b) {
            if (labels[b] == c) {                       // wave-uniform branch
                float4 xv = ((const float4*)(x + (size_t)b * D_N))[t];
                sx.x += xv.x; sx.y += xv.y; sx.z += xv.z; sx.w += xv.w;
            }
        }
        float inv = 1.0f / (float)(n + 1);
        float ac = 1.0f - ALPHA * (float)n * inv;       // centers coefficient
        float bc = ALPHA * inv;                         // sum_x coefficient
        res.x = cv.x * ac + sx.x * bc;
        res.y = cv.y * ac + sx.y * bc;
        res.z = cv.z * ac + sx.z * bc;
        res.w = cv.w * ac + sx.w * bc;
    }
    ((float4*)(newc + (size_t)c * D_N))[t] = res;
}

extern "C" void kernel_launch(void* const* d_in, const int* in_sizes, int n_in,
                              void* d_out, int out_size, void* d_ws, size_t ws_size,
                              hipStream_t stream) {
    const float* x       = (const float*)d_in[0];   // [B, D]
    const float* onehot  = (const float*)d_in[1];   // [B, C]
    const float* centers = (const float*)d_in[2];   // [C, D]
    float* out    = (float*)d_out;
    float* result = out;                            // [B, 1] -> 256 floats
    float* newc   = out + B_N;                      // [C, D]

    int* counts = (int*)d_ws;                       // C ints (200 KB)
    int* labels = counts + C_N;                     // B ints

    hipMemsetAsync(counts, 0, C_N * sizeof(int), stream);

    const int total4 = B_N * C_N / 4;               // 3.2M
    find_labels<<<(total4 + 255) / 256, 256, 0, stream>>>(onehot, labels, counts);
    sq_dist<<<B_N, 128, 0, stream>>>(x, centers, labels, result);
    update_centers<<<C_N, 128, 0, stream>>>(x, centers, labels, counts, newc);
}